// Round 8
// baseline (863.015 us; speedup 1.0000x reference)
//
#include <hip/hip_runtime.h>
#include <math.h>

#define BATCH 128
#define HH 256
#define WW 256
#define HW (HH * WW)
#define HW4 (HW / 4)   // 16384 float4 per plane
#define CHUNKS 64      // blocks per batch (256 float4 per plane each)
#define NKPT 68

typedef float fx4 __attribute__((ext_vector_type(4)));

__device__ inline double wave_sum64(double v) {
#pragma unroll
    for (int off = 32; off > 0; off >>= 1) v += __shfl_xor(v, off);
    return v;
}

// ---------------------------------------------------------------------------
// Per-batch similarity transform, wave-parallel (identical math to the
// verified R5 version, absmax 0.03125). Lane-parallel gather + one butterfly
// reduction pass; lane 0 runs the 3x3 Jacobi polar decomposition in double.
// ---------------------------------------------------------------------------
__device__ void tform_wave(int tb, int lane, const float* __restrict__ Offset,
                           const float* __restrict__ Posmap,
                           const float* __restrict__ meanp,
                           const int* __restrict__ uv, float* __restrict__ RT) {
    const float* offb = Offset + (size_t)tb * 3 * HW;
    const float* dstb = Posmap + (size_t)tb * 3 * HW;
    const bool has1 = lane < (NKPT - 64);

    double s0[3], d0[3], s1[3] = {0, 0, 0}, d1[3] = {0, 0, 0};
    {
        const int q0 = uv[lane * 2 + 0] * WW + uv[lane * 2 + 1];
#pragma unroll
        for (int i = 0; i < 3; i++) {
            s0[i] = (double)offb[(size_t)i * HW + q0] * 6.0 +
                    (double)meanp[(size_t)i * HW + q0];
            d0[i] = (double)dstb[(size_t)i * HW + q0];
        }
        if (has1) {
            const int k1 = lane + 64;
            const int q1 = uv[k1 * 2 + 0] * WW + uv[k1 * 2 + 1];
#pragma unroll
            for (int i = 0; i < 3; i++) {
                s1[i] = (double)offb[(size_t)i * HW + q1] * 6.0 +
                        (double)meanp[(size_t)i * HW + q1];
                d1[i] = (double)dstb[(size_t)i * HW + q1];
            }
        }
    }

    double s33[3], d33[3];
#pragma unroll
    for (int i = 0; i < 3; i++) {
        s33[i] = __shfl(s0[i], 33);
        d33[i] = __shfl(d0[i], 33);
    }

    double ns0 = 0, nd0 = 0, ns1 = 0, nd1 = 0;
    double ssum[3], dsum[3], P[3][3];
#pragma unroll
    for (int i = 0; i < 3; i++) {
        double es = s0[i] - s33[i], ed = d0[i] - d33[i];
        ns0 += es * es;
        nd0 += ed * ed;
        es = s1[i] - s33[i];
        ed = d1[i] - d33[i];
        ns1 += es * es;
        nd1 += ed * ed;
        ssum[i] = s0[i] + s1[i];
        dsum[i] = d0[i] + d1[i];
#pragma unroll
        for (int j = 0; j < 3; j++) P[i][j] = s0[i] * d0[j] + s1[i] * d1[j];
    }
    double sd1p = sqrt(ns0) + (has1 ? sqrt(ns1) : 0.0);
    double sd2p = sqrt(nd0) + (has1 ? sqrt(nd1) : 0.0);

    const double sd1 = wave_sum64(sd1p);
    const double sd2 = wave_sum64(sd2p);
#pragma unroll
    for (int i = 0; i < 3; i++) {
        ssum[i] = wave_sum64(ssum[i]);
        dsum[i] = wave_sum64(dsum[i]);
    }
#pragma unroll
    for (int i = 0; i < 3; i++)
#pragma unroll
        for (int j = 0; j < 3; j++) P[i][j] = wave_sum64(P[i][j]);

    if (lane != 0) return;

    const double s = sd2 / sd1;
    double sbar[3], dbar[3];
#pragma unroll
    for (int i = 0; i < 3; i++) {
        sbar[i] = ssum[i] / NKPT;
        dbar[i] = dsum[i] / NKPT;
    }
    double Hm[3][3];
    for (int i = 0; i < 3; i++)
        for (int j = 0; j < 3; j++)
            Hm[i][j] = P[i][j] - (double)NKPT * sbar[i] * dbar[j];

    double A[3][3];
    for (int i = 0; i < 3; i++)
        for (int j = 0; j < 3; j++) {
            double acc = 0;
            for (int kk = 0; kk < 3; kk++) acc += Hm[kk][i] * Hm[kk][j];
            A[i][j] = acc;
        }

    double V[3][3] = {{1, 0, 0}, {0, 1, 0}, {0, 0, 1}};
    for (int sweep = 0; sweep < 12; ++sweep) {
        double off = fabs(A[0][1]) + fabs(A[0][2]) + fabs(A[1][2]);
        double diag = fabs(A[0][0]) + fabs(A[1][1]) + fabs(A[2][2]);
        if (off <= diag * 1e-15) break;
        for (int pp = 0; pp < 2; pp++)
            for (int q = pp + 1; q < 3; q++) {
                double apq = A[pp][q];
                if (fabs(apq) < 1e-300) continue;
                double theta = (A[q][q] - A[pp][pp]) / (2.0 * apq);
                double t = (theta >= 0.0 ? 1.0 : -1.0) /
                           (fabs(theta) + sqrt(theta * theta + 1.0));
                double cc = 1.0 / sqrt(t * t + 1.0);
                double sn = t * cc;
                A[pp][pp] -= t * apq;
                A[q][q] += t * apq;
                A[pp][q] = 0.0;
                A[q][pp] = 0.0;
                int r = 3 - pp - q;
                double arp = A[r][pp], arq = A[r][q];
                A[r][pp] = A[pp][r] = cc * arp - sn * arq;
                A[r][q] = A[q][r] = sn * arp + cc * arq;
#pragma unroll
                for (int rr = 0; rr < 3; rr++) {
                    double vrp = V[rr][pp], vrq = V[rr][q];
                    V[rr][pp] = cc * vrp - sn * vrq;
                    V[rr][q] = sn * vrp + cc * vrq;
                }
            }
    }
    double isig[3];
#pragma unroll
    for (int i = 0; i < 3; i++) {
        double l = A[i][i];
        if (l < 1e-30) l = 1e-30;
        isig[i] = 1.0 / sqrt(l);
    }
    double Wm[3][3];
    for (int i = 0; i < 3; i++)
        for (int j = 0; j < 3; j++) {
            double acc = 0;
            for (int kk = 0; kk < 3; kk++) acc += V[i][kk] * V[j][kk] * isig[kk];
            Wm[i][j] = acc;
        }
    double R[3][3];
    for (int i = 0; i < 3; i++)
        for (int j = 0; j < 3; j++) {
            double acc = 0;
            for (int kk = 0; kk < 3; kk++) acc += Wm[i][kk] * Hm[j][kk];
            R[i][j] = acc;
        }

    float* rt = RT + tb * 12;
    for (int j = 0; j < 3; j++) {
        for (int i = 0; i < 3; i++) rt[j * 3 + i] = (float)(R[j][i] * s);
        double tj = dbar[j];
        for (int i = 0; i < 3; i++) tj -= s * sbar[i] * R[j][i];
        rt[9 + j] = (float)tj;
    }
}

// ---------------------------------------------------------------------------
// Fused kernel, 8192 independent blocks (one chunk per plane each — the
// proven R5 memory engine). Per batch, the FIRST block to arrive claims the
// tform via atomicCAS(flags[b],0,1), computes it inline on wave 0, and
// release-publishes flags[b]=2. Other blocks acquire-spin; the claimant is
// resident by construction (it executed the CAS) and independent of the
// spinners, so this is deadlock-free under any dispatch order. All blocks
// issue their 6 streaming loads BEFORE the claim/spin so the tform latency
// overlaps the HBM ramp.
// flags[] is zeroed by a 512-B hipMemsetAsync each call (deterministic).
// ---------------------------------------------------------------------------
__global__ __launch_bounds__(256, 4) void fused_kernel(
    const float* __restrict__ Offset, const float* __restrict__ Posmap,
    const float* __restrict__ meanp, const int* __restrict__ uv,
    float* __restrict__ Out, float* __restrict__ WS) {
    int* flags = (int*)WS;          // 128 ints (zeroed per call)
    float* RT = WS + BATCH;         // 128 * 12 floats, written by claimants

    const int blk = blockIdx.x;
    const int tid = threadIdx.x;
    const int b = blk >> 6;                    // batch
    const int p = (blk & 63) * 256 + tid;      // float4 index within plane
    const size_t base = (size_t)b * 3 * HW4;

    const fx4* Off4 = (const fx4*)Offset;
    const fx4* Mean4 = (const fx4*)meanp;
    fx4* Out4 = (fx4*)Out;

    // Streaming loads first — in flight during claim/tform/spin.
    fx4 o0 = Off4[base + p];
    fx4 o1 = Off4[base + HW4 + p];
    fx4 o2 = Off4[base + 2 * HW4 + p];
    fx4 m0 = Mean4[p];
    fx4 m1 = Mean4[HW4 + p];
    fx4 m2 = Mean4[2 * HW4 + p];

    __shared__ int sclaim;
    if (tid == 0) sclaim = (atomicCAS(&flags[b], 0, 1) == 0) ? 1 : 0;
    __syncthreads();

    if (sclaim && tid < 64) {
        tform_wave(b, tid, Offset, Posmap, meanp, uv, RT);
        if (tid == 0) {
            __threadfence();  // release RT to device scope
            __hip_atomic_store(&flags[b], 2, __ATOMIC_RELEASE,
                               __HIP_MEMORY_SCOPE_AGENT);
        }
    }

    if (tid == 0) {
        while (__hip_atomic_load(&flags[b], __ATOMIC_ACQUIRE,
                                 __HIP_MEMORY_SCOPE_AGENT) != 2) {
            __builtin_amdgcn_s_sleep(2);
        }
    }
    __syncthreads();

    const float* rt = RT + b * 12;
    const float r00 = rt[0], r01 = rt[1], r02 = rt[2];
    const float r10 = rt[3], r11 = rt[4], r12 = rt[5];
    const float r20 = rt[6], r21 = rt[7], r22 = rt[8];
    const float t0 = rt[9], t1 = rt[10], t2 = rt[11];

    fx4 y0, y1, y2;
#pragma unroll
    for (int e = 0; e < 4; e++) {
        float x0 = fmaf(o0[e], 6.0f, m0[e]);
        float x1 = fmaf(o1[e], 6.0f, m1[e]);
        float x2 = fmaf(o2[e], 6.0f, m2[e]);
        y0[e] = fmaf(x0, r00, fmaf(x1, r01, fmaf(x2, r02, t0)));
        y1[e] = fmaf(x0, r10, fmaf(x1, r11, fmaf(x2, r12, t1)));
        y2[e] = fmaf(x0, r20, fmaf(x1, r21, fmaf(x2, r22, t2)));
    }
    __builtin_nontemporal_store(y0, &Out4[base + p]);
    __builtin_nontemporal_store(y1, &Out4[base + HW4 + p]);
    __builtin_nontemporal_store(y2, &Out4[base + 2 * HW4 + p]);
}

extern "C" void kernel_launch(void* const* d_in, const int* in_sizes, int n_in,
                              void* d_out, int out_size, void* d_ws,
                              size_t ws_size, hipStream_t stream) {
    const float* Offset = (const float*)d_in[0];
    const float* Posmap = (const float*)d_in[1];
    const float* meanp = (const float*)d_in[2];
    const int* uv = (const int*)d_in[3];
    float* out = (float*)d_out;
    float* WS = (float*)d_ws;  // [128 flags][128*12 RT floats]

    hipMemsetAsync(WS, 0, BATCH * sizeof(int), stream);
    fused_kernel<<<BATCH * CHUNKS, 256, 0, stream>>>(Offset, Posmap, meanp, uv,
                                                     out, WS);
}

// Round 9
// 41.721 us; speedup vs baseline: 20.6852x; 20.6852x over previous
//
#include <hip/hip_runtime.h>
#include <math.h>

#define BATCH 128
#define HH 256
#define WW 256
#define HW (HH * WW)
#define HW4 (HW / 4)   // 16384 float4 per plane
#define NKPT 68

typedef float fx4 __attribute__((ext_vector_type(4)));

__device__ inline double wave_sum64(double v) {
#pragma unroll
    for (int off = 32; off > 0; off >>= 1) v += __shfl_xor(v, off);
    return v;
}

// ---------------------------------------------------------------------------
// Kernel A: per-batch similarity transform. One wave per batch, 128 blocks.
// Lane-parallel gather + one butterfly-reduction pass (verified R5 math).
// Lane 0 then computes R = polar(Hm^T) via det-scaled NEWTON iteration
// X <- (uX + cof(X)/(u det))/2  (quadratic convergence, ~500-cycle chain,
// replacing the ~10k-cycle serial Jacobi). polar(Hm^T) = V U^T of the SVD.
// Writes 12 floats per batch: Rs[3][3] row-major (already *s), t[3].
// ---------------------------------------------------------------------------
__global__ __launch_bounds__(64, 1) void tform_kernel(
    const float* __restrict__ Offset, const float* __restrict__ Posmap,
    const float* __restrict__ meanp, const int* __restrict__ uv,
    float* __restrict__ RT) {
    const int b = blockIdx.x;
    const int lane = threadIdx.x;
    const float* offb = Offset + (size_t)b * 3 * HW;
    const float* dstb = Posmap + (size_t)b * 3 * HW;
    const bool has1 = lane < (NKPT - 64);

    double s0[3], d0[3], s1[3] = {0, 0, 0}, d1[3] = {0, 0, 0};
    {
        const int q0 = uv[lane * 2 + 0] * WW + uv[lane * 2 + 1];
#pragma unroll
        for (int i = 0; i < 3; i++) {
            s0[i] = (double)offb[(size_t)i * HW + q0] * 6.0 +
                    (double)meanp[(size_t)i * HW + q0];
            d0[i] = (double)dstb[(size_t)i * HW + q0];
        }
        if (has1) {
            const int k1 = lane + 64;
            const int q1 = uv[k1 * 2 + 0] * WW + uv[k1 * 2 + 1];
#pragma unroll
            for (int i = 0; i < 3; i++) {
                s1[i] = (double)offb[(size_t)i * HW + q1] * 6.0 +
                        (double)meanp[(size_t)i * HW + q1];
                d1[i] = (double)dstb[(size_t)i * HW + q1];
            }
        }
    }

    double s33[3], d33[3];
#pragma unroll
    for (int i = 0; i < 3; i++) {
        s33[i] = __shfl(s0[i], 33);
        d33[i] = __shfl(d0[i], 33);
    }

    double ns0 = 0, nd0 = 0, ns1 = 0, nd1 = 0;
    double ssum[3], dsum[3], P[3][3];
#pragma unroll
    for (int i = 0; i < 3; i++) {
        double es = s0[i] - s33[i], ed = d0[i] - d33[i];
        ns0 += es * es;
        nd0 += ed * ed;
        es = s1[i] - s33[i];
        ed = d1[i] - d33[i];
        ns1 += es * es;
        nd1 += ed * ed;
        ssum[i] = s0[i] + s1[i];
        dsum[i] = d0[i] + d1[i];
#pragma unroll
        for (int j = 0; j < 3; j++) P[i][j] = s0[i] * d0[j] + s1[i] * d1[j];
    }
    double sd1p = sqrt(ns0) + (has1 ? sqrt(ns1) : 0.0);
    double sd2p = sqrt(nd0) + (has1 ? sqrt(nd1) : 0.0);

    const double sd1 = wave_sum64(sd1p);
    const double sd2 = wave_sum64(sd2p);
#pragma unroll
    for (int i = 0; i < 3; i++) {
        ssum[i] = wave_sum64(ssum[i]);
        dsum[i] = wave_sum64(dsum[i]);
    }
#pragma unroll
    for (int i = 0; i < 3; i++)
#pragma unroll
        for (int j = 0; j < 3; j++) P[i][j] = wave_sum64(P[i][j]);

    if (lane != 0) return;

    const double s = sd2 / sd1;
    double sbar[3], dbar[3];
#pragma unroll
    for (int i = 0; i < 3; i++) {
        sbar[i] = ssum[i] / NKPT;
        dbar[i] = dsum[i] / NKPT;
    }
    double Hm[3][3];
#pragma unroll
    for (int i = 0; i < 3; i++)
#pragma unroll
        for (int j = 0; j < 3; j++)
            Hm[i][j] = P[i][j] - (double)NKPT * sbar[i] * dbar[j];

    // X = Hm^T ; Newton polar iteration with determinant scaling.
    double X[3][3];
#pragma unroll
    for (int i = 0; i < 3; i++)
#pragma unroll
        for (int j = 0; j < 3; j++) X[i][j] = Hm[j][i];

#pragma unroll
    for (int it = 0; it < 9; ++it) {
        // Cofactor matrix C (so that X^{-T} = C / det).
        double C[3][3];
        C[0][0] = X[1][1] * X[2][2] - X[1][2] * X[2][1];
        C[0][1] = X[1][2] * X[2][0] - X[1][0] * X[2][2];
        C[0][2] = X[1][0] * X[2][1] - X[1][1] * X[2][0];
        C[1][0] = X[0][2] * X[2][1] - X[0][1] * X[2][2];
        C[1][1] = X[0][0] * X[2][2] - X[0][2] * X[2][0];
        C[1][2] = X[0][1] * X[2][0] - X[0][0] * X[2][1];
        C[2][0] = X[0][1] * X[1][2] - X[0][2] * X[1][1];
        C[2][1] = X[0][2] * X[1][0] - X[0][0] * X[1][2];
        C[2][2] = X[0][0] * X[1][1] - X[0][1] * X[1][0];
        double det =
            X[0][0] * C[0][0] + X[0][1] * C[0][1] + X[0][2] * C[0][2];
        double ad = fabs(det);
        if (ad < 1e-250) ad = 1e-250;
        const double mu = 1.0 / cbrt(ad);          // |det(mu X)| = 1
        const double inv = 1.0 / (mu * det);       // (mu X)^{-T} = C * inv
#pragma unroll
        for (int i = 0; i < 3; i++)
#pragma unroll
            for (int j = 0; j < 3; j++)
                X[i][j] = 0.5 * (mu * X[i][j] + C[i][j] * inv);
    }
    // X is now the orthogonal polar factor R = V U^T.

    float* rt = RT + b * 12;
    for (int j = 0; j < 3; j++) {
        for (int i = 0; i < 3; i++) rt[j * 3 + i] = (float)(X[j][i] * s);
        double tj = dbar[j];
        for (int i = 0; i < 3; i++) tj -= s * sbar[i] * X[j][i];
        rt[9 + j] = (float)tj;
    }
}

// ---------------------------------------------------------------------------
// Kernel B: out[b,j,h,w] = sum_i (Offset[b,i,h,w]*6 + mean[i,h,w]) * Rs[j][i]
//                          + t[j]
// 4096 blocks, 2 chunks per block. All 12 loads issued up-front (12-deep
// MLP per wave); stores are nontemporal fire-and-forget.
// ---------------------------------------------------------------------------
__global__ __launch_bounds__(256, 4) void apply_kernel(
    const fx4* __restrict__ Off, const fx4* __restrict__ Mean,
    const float* __restrict__ RT, fx4* __restrict__ Out) {
    const int PAIRS = HW4 / 512;  // 32 chunk-pairs per batch
    const int b = blockIdx.x / PAIRS;
    const int w = blockIdx.x % PAIRS;
    const int p0 = w * 512 + threadIdx.x;
    const int p1 = p0 + 256;
    const size_t base = (size_t)b * 3 * HW4;

    // HBM streaming loads first (deep MLP), then L2-resident mean loads.
    fx4 a0 = Off[base + p0];
    fx4 a1 = Off[base + HW4 + p0];
    fx4 a2 = Off[base + 2 * HW4 + p0];
    fx4 b0 = Off[base + p1];
    fx4 b1 = Off[base + HW4 + p1];
    fx4 b2 = Off[base + 2 * HW4 + p1];
    fx4 ma0 = Mean[p0];
    fx4 ma1 = Mean[HW4 + p0];
    fx4 ma2 = Mean[2 * HW4 + p0];
    fx4 mb0 = Mean[p1];
    fx4 mb1 = Mean[HW4 + p1];
    fx4 mb2 = Mean[2 * HW4 + p1];

    const float* rt = RT + b * 12;
    const float r00 = rt[0], r01 = rt[1], r02 = rt[2];
    const float r10 = rt[3], r11 = rt[4], r12 = rt[5];
    const float r20 = rt[6], r21 = rt[7], r22 = rt[8];
    const float t0 = rt[9], t1 = rt[10], t2 = rt[11];

    fx4 y0, y1, y2, z0, z1, z2;
#pragma unroll
    for (int e = 0; e < 4; e++) {
        float x0 = fmaf(a0[e], 6.0f, ma0[e]);
        float x1 = fmaf(a1[e], 6.0f, ma1[e]);
        float x2 = fmaf(a2[e], 6.0f, ma2[e]);
        y0[e] = fmaf(x0, r00, fmaf(x1, r01, fmaf(x2, r02, t0)));
        y1[e] = fmaf(x0, r10, fmaf(x1, r11, fmaf(x2, r12, t1)));
        y2[e] = fmaf(x0, r20, fmaf(x1, r21, fmaf(x2, r22, t2)));
        float u0 = fmaf(b0[e], 6.0f, mb0[e]);
        float u1 = fmaf(b1[e], 6.0f, mb1[e]);
        float u2 = fmaf(b2[e], 6.0f, mb2[e]);
        z0[e] = fmaf(u0, r00, fmaf(u1, r01, fmaf(u2, r02, t0)));
        z1[e] = fmaf(u0, r10, fmaf(u1, r11, fmaf(u2, r12, t1)));
        z2[e] = fmaf(u0, r20, fmaf(u1, r21, fmaf(u2, r22, t2)));
    }

    __builtin_nontemporal_store(y0, &Out[base + p0]);
    __builtin_nontemporal_store(y1, &Out[base + HW4 + p0]);
    __builtin_nontemporal_store(y2, &Out[base + 2 * HW4 + p0]);
    __builtin_nontemporal_store(z0, &Out[base + p1]);
    __builtin_nontemporal_store(z1, &Out[base + HW4 + p1]);
    __builtin_nontemporal_store(z2, &Out[base + 2 * HW4 + p1]);
}

extern "C" void kernel_launch(void* const* d_in, const int* in_sizes, int n_in,
                              void* d_out, int out_size, void* d_ws,
                              size_t ws_size, hipStream_t stream) {
    const float* Offset = (const float*)d_in[0];
    const float* Posmap = (const float*)d_in[1];
    const float* meanp = (const float*)d_in[2];
    const int* uv = (const int*)d_in[3];
    float* out = (float*)d_out;
    float* RT = (float*)d_ws;  // 128 * 12 floats

    tform_kernel<<<BATCH, 64, 0, stream>>>(Offset, Posmap, meanp, uv, RT);
    apply_kernel<<<BATCH * (HW4 / 512), 256, 0, stream>>>(
        (const fx4*)Offset, (const fx4*)meanp, RT, (fx4*)out);
}